// Round 6
// baseline (420.538 us; speedup 1.0000x reference)
//
#include <hip/hip_runtime.h>

#define H 16
#define D 24
#define DS 384
#define CZ 128
#define S 512
#define EPSV 1e-5f

// ================= Kernel 1: tiled Q/K/VT/G projections (baseline, passing) =================
__global__ __launch_bounds__(256) void proj_kernel(
    const float* __restrict__ s, const float* __restrict__ q_w, const float* __restrict__ q_b,
    const float* __restrict__ k_w, const float* __restrict__ v_w, const float* __restrict__ g_w,
    float* __restrict__ Q, float* __restrict__ K, float* __restrict__ VT, float* __restrict__ G)
{
    const int b = blockIdx.x;
    const int mat = b / 48;          // 0:Q 1:K 2:V 3:G
    const int t = b % 48;
    const int by = t / 6, bx = t % 6;
    const float* w = (mat == 0) ? q_w : (mat == 1) ? k_w : (mat == 2) ? v_w : g_w;

    __shared__ float As[32][68];
    __shared__ float Ws[32][68];

    const int tid = threadIdx.x;
    const int tx = tid & 15, ty = tid >> 4;
    const int r8 = tid >> 3;
    const int c4 = tid & 7;

    float acc[4][4] = {};
    for (int kc = 0; kc < DS; kc += 32) {
        __syncthreads();
#pragma unroll
        for (int pass = 0; pass < 2; ++pass) {
            int r = r8 + pass * 32;
            float4 sv = *(const float4*)(s + (by * 64 + r) * DS + kc + c4 * 4);
            float4 wv = *(const float4*)(w + (bx * 64 + r) * DS + kc + c4 * 4);
            As[c4 * 4 + 0][r] = sv.x; As[c4 * 4 + 1][r] = sv.y;
            As[c4 * 4 + 2][r] = sv.z; As[c4 * 4 + 3][r] = sv.w;
            Ws[c4 * 4 + 0][r] = wv.x; Ws[c4 * 4 + 1][r] = wv.y;
            Ws[c4 * 4 + 2][r] = wv.z; Ws[c4 * 4 + 3][r] = wv.w;
        }
        __syncthreads();
#pragma unroll
        for (int k = 0; k < 32; ++k) {
            float4 a4 = *(const float4*)&As[k][ty * 4];
            float4 b4 = *(const float4*)&Ws[k][tx * 4];
            acc[0][0] += a4.x * b4.x; acc[0][1] += a4.x * b4.y; acc[0][2] += a4.x * b4.z; acc[0][3] += a4.x * b4.w;
            acc[1][0] += a4.y * b4.x; acc[1][1] += a4.y * b4.y; acc[1][2] += a4.y * b4.z; acc[1][3] += a4.y * b4.w;
            acc[2][0] += a4.z * b4.x; acc[2][1] += a4.z * b4.y; acc[2][2] += a4.z * b4.z; acc[2][3] += a4.z * b4.w;
            acc[3][0] += a4.w * b4.x; acc[3][1] += a4.w * b4.y; acc[3][2] += a4.w * b4.z; acc[3][3] += a4.w * b4.w;
        }
    }

    const int r0 = by * 64 + ty * 4;
    const int c0 = bx * 64 + tx * 4;
    if (mat == 2) {
#pragma unroll
        for (int ii = 0; ii < 4; ++ii)
#pragma unroll
            for (int jj = 0; jj < 4; ++jj)
                VT[(c0 + jj) * S + (r0 + ii)] = acc[ii][jj];
    } else {
        float* dst = (mat == 0) ? Q : (mat == 1) ? K : G;
#pragma unroll
        for (int ii = 0; ii < 4; ++ii) {
            float4 v;
            v.x = acc[ii][0]; v.y = acc[ii][1]; v.z = acc[ii][2]; v.w = acc[ii][3];
            if (mat == 0) {
                v.x += q_b[c0 + 0]; v.y += q_b[c0 + 1]; v.z += q_b[c0 + 2]; v.w += q_b[c0 + 3];
            } else if (mat == 3) {
                v.x = 1.f / (1.f + __expf(-v.x)); v.y = 1.f / (1.f + __expf(-v.y));
                v.z = 1.f / (1.f + __expf(-v.z)); v.w = 1.f / (1.f + __expf(-v.w));
            }
            *(float4*)(dst + (r0 + ii) * DS + c0) = v;
        }
    }
}

// ================= Kernel 2a: staged-z + register-stationary-a scores =================
// grid 2048: b = q*4 + jt, 128 key rows/block. 4 waves x 4 heads, lane = row-in-batch,
// 2 batches. z staged into LDS in four 32-ch stages via COALESCED 1-KB wave loads
// (8 lines/inst vs 64 for the gather pattern that killed r4/r5). LDS stride 36 floats
// (4 mod 32) = bank-optimal 8-phase b128. a loaded per chunk as wave-uniform broadcast
// (16B, conflict-free) into regs, reused over 2 batches. LN stats + qk in-lane.
// buf aliases the dead zs region -> ~28 KB LDS -> 4-5 blocks/CU.
__global__ __launch_bounds__(256) void score_kernel(
    const float* __restrict__ z, const float* __restrict__ seq_mask,
    const float* __restrict__ z_ln_w, const float* __restrict__ z_ln_b,
    const float* __restrict__ z_w,
    const float* __restrict__ Q, const float* __restrict__ K,
    float* __restrict__ scores)
{
    const int b = blockIdx.x;
    const int q = b >> 2;
    const int j0 = (b & 3) * 128;
    const int tid = threadIdx.x;
    const int w = tid >> 6;        // wave id -> head quad
    const int lane = tid & 63;     // row within batch
    const int h0 = w * 4;

    __shared__ float a_s[H][CZ + 4];      // folded lnw*zw          8.4 KB
    __shared__ float AhBh[2][H];          //                        128 B
    __shared__ float qrow[DS];            //                        1.5 KB
    __shared__ float zs[128 * 36];        // 32-ch z stage          18.4 KB (buf aliases)

    // ---- Phase 0: stage a_s (+Ah/Bh) and qrow ----
    {
        const int h = tid >> 4;           // 0..15
        const int c8 = (tid & 15) * 8;    // 8 channels each
        float A = 0.f, Bv = 0.f;
#pragma unroll
        for (int p = 0; p < 2; ++p) {
            float4 wz = *(const float4*)(z_w + h * CZ + c8 + p * 4);
            float4 lw = *(const float4*)(z_ln_w + c8 + p * 4);
            float4 lb = *(const float4*)(z_ln_b + c8 + p * 4);
            float4 a;
            a.x = lw.x * wz.x; a.y = lw.y * wz.y; a.z = lw.z * wz.z; a.w = lw.w * wz.w;
            *(float4*)&a_s[h][c8 + p * 4] = a;
            A += a.x + a.y + a.z + a.w;
            Bv += lb.x * wz.x + lb.y * wz.y + lb.z * wz.z + lb.w * wz.w;
        }
#pragma unroll
        for (int m = 1; m < 16; m <<= 1) {
            A += __shfl_xor(A, m);
            Bv += __shfl_xor(Bv, m);
        }
        if ((tid & 15) == 0) { AhBh[0][h] = A; AhBh[1][h] = Bv; }
    }
    for (int i = tid; i < DS; i += 256) qrow[i] = Q[q * DS + i];

    float accz[4][2];                 // [head][batch] dza accumulators
    float s1[2] = {0.f, 0.f}, s2[2] = {0.f, 0.f};
#pragma unroll
    for (int i = 0; i < 4; ++i) { accz[i][0] = 0.f; accz[i][1] = 0.f; }

    const float* zq = z + ((long)q * S + j0) * CZ;

    // ---- dza GEMM + LN stats: 4 staged 32-ch quarters, 2 chunks each ----
    for (int st = 0; st < 4; ++st) {
        const int c0 = st * 32;
        __syncthreads();              // previous stage's reads complete
#pragma unroll
        for (int it = 0; it < 4; ++it) {
            const int idx = it * 256 + tid;
            const int row = idx >> 3, fg = idx & 7;
            float4 v = *(const float4*)(zq + (long)row * CZ + c0 + fg * 4);
            *(float4*)&zs[row * 36 + fg * 4] = v;
        }
        __syncthreads();

#pragma unroll
        for (int ccl = 0; ccl < 2; ++ccl) {
            const int cb = ccl * 16;
            float4 areg[4][4];        // 4 heads x 16 ch, broadcast-read once per wave
#pragma unroll
            for (int i = 0; i < 4; ++i)
#pragma unroll
                for (int t = 0; t < 4; ++t)
                    areg[i][t] = *(const float4*)&a_s[h0 + i][c0 + cb + t * 4];

#pragma unroll
            for (int bt = 0; bt < 2; ++bt) {
                const int row = bt * 64 + lane;
                float4 zf[4];
#pragma unroll
                for (int t = 0; t < 4; ++t)
                    zf[t] = *(const float4*)&zs[row * 36 + cb + t * 4];
#pragma unroll
                for (int t = 0; t < 4; ++t) {
                    s1[bt] += zf[t].x + zf[t].y + zf[t].z + zf[t].w;
                    s2[bt] += zf[t].x * zf[t].x + zf[t].y * zf[t].y
                            + zf[t].z * zf[t].z + zf[t].w * zf[t].w;
                }
#pragma unroll
                for (int i = 0; i < 4; ++i) {
                    float a = 0.f;
#pragma unroll
                    for (int t = 0; t < 4; ++t)
                        a += zf[t].x * areg[i][t].x + zf[t].y * areg[i][t].y
                           + zf[t].z * areg[i][t].z + zf[t].w * areg[i][t].w;
                    accz[i][bt] += a;
                }
            }
        }
    }

    // ---- qk: per head, Q broadcast from LDS, K per-lane row (L1/L2-friendly) ----
    float qk[4][2];
#pragma unroll
    for (int i = 0; i < 4; ++i) {
        const int h = h0 + i;
        float4 qreg[6];
#pragma unroll
        for (int t = 0; t < 6; ++t) qreg[t] = *(const float4*)&qrow[h * D + t * 4];
#pragma unroll
        for (int bt = 0; bt < 2; ++bt) {
            const int row = bt * 64 + lane;
            const float4* kp = (const float4*)(K + (long)(j0 + row) * DS + h * D);
            float a = 0.f;
#pragma unroll
            for (int t = 0; t < 6; ++t) {
                float4 kv = kp[t];
                a += kv.x * qreg[t].x + kv.y * qreg[t].y + kv.z * qreg[t].z + kv.w * qreg[t].w;
            }
            qk[i][bt] = a;
        }
    }

    // ---- epilogue: LN affine + combine; buf aliases zs (dead after barrier) ----
    __syncthreads();
    float* buf = zs;                  // [H][132]
    const float scale = 0.2041241452319315f;  // 1/sqrt(24)
#pragma unroll
    for (int bt = 0; bt < 2; ++bt) {
        const int row = bt * 64 + lane;
        const float mu = s1[bt] * (1.f / 128.f);
        const float rs = rsqrtf(s2[bt] * (1.f / 128.f) - mu * mu + EPSV);
        const float mk = seq_mask[j0 + row];
#pragma unroll
        for (int i = 0; i < 4; ++i) {
            const int h = h0 + i;
            const float bias = rs * accz[i][bt] - mu * rs * AhBh[0][h] + AhBh[1][h];
            buf[h * 132 + row] = qk[i][bt] * scale + bias + mk;
        }
    }
    __syncthreads();

    // coalesced store: 512 float4 slots, 2 per thread
#pragma unroll
    for (int it = 0; it < 2; ++it) {
        const int idx = it * 256 + tid;
        const int h = idx >> 5, j4 = idx & 31;
        float4 v = *(const float4*)&buf[h * 132 + j4 * 4];
        *(float4*)(scores + ((q << 4) + h) * S + j0 + j4 * 4) = v;
    }
}

// ================= Kernel 2b: softmax + PV + gate (baseline, passing) =================
__global__ __launch_bounds__(256) void spv_kernel(
    const float* __restrict__ scores, const float* __restrict__ VT,
    const float* __restrict__ G, float* __restrict__ og)
{
    const int q = blockIdx.x;
    const int tid = threadIdx.x;
    const int wv = tid >> 6;
    const int lane = tid & 63;

    __shared__ float sc[H][S + 4];
    __shared__ float opart[4][DS];
    __shared__ float inv_l[H];

    for (int i = tid; i < H * (S / 4); i += 256) {
        int row = i >> 7, f4 = i & 127;
        float4 v = ((const float4*)(scores + ((q << 4) + row) * S))[f4];
        *(float4*)&sc[row][f4 * 4] = v;
    }
    __syncthreads();

#pragma unroll
    for (int i = 0; i < 4; ++i) {
        int h = wv * 4 + i;
        float m = -1e30f;
        for (int j = lane; j < S; j += 64) m = fmaxf(m, sc[h][j]);
#pragma unroll
        for (int mk = 1; mk < 64; mk <<= 1) m = fmaxf(m, __shfl_xor(m, mk));
        float sum = 0.f;
        for (int j = lane; j < S; j += 64) {
            float p = __expf(sc[h][j] - m);
            sc[h][j] = p;
            sum += p;
        }
#pragma unroll
        for (int mk = 1; mk < 64; mk <<= 1) sum += __shfl_xor(sum, mk);
        if (lane == 0) inv_l[h] = 1.f / sum;
    }
    __syncthreads();

#pragma unroll
    for (int ii = 0; ii < 6; ++ii) {
        int idx = ii * 64 + lane;
        int h = idx / 24;
        float acc = 0.f;
        const float4* vt4 = (const float4*)(VT + idx * S + wv * 128);
        const float4* sc4 = (const float4*)&sc[h][wv * 128];
#pragma unroll
        for (int t = 0; t < 32; ++t) {
            float4 p = sc4[t];
            float4 v = vt4[t];
            acc += p.x * v.x + p.y * v.y + p.z * v.z + p.w * v.w;
        }
        opart[wv][idx] = acc;
    }
    __syncthreads();
    for (int i = tid; i < DS; i += 256) {
        float o = opart[0][i] + opart[1][i] + opart[2][i] + opart[3][i];
        int h = i / 24;
        og[q * DS + i] = o * inv_l[h] * G[q * DS + i];
    }
}

// ================= Kernel 3: tiled output projection (baseline, passing) =================
__global__ __launch_bounds__(256) void out_kernel(
    const float* __restrict__ og, const float* __restrict__ o_w, float* __restrict__ out)
{
    const int b = blockIdx.x;
    const int by = b / 6, bx = b % 6;

    __shared__ float As[32][68];
    __shared__ float Ws[32][68];

    const int tid = threadIdx.x;
    const int tx = tid & 15, ty = tid >> 4;
    const int r8 = tid >> 3;
    const int c4 = tid & 7;

    float acc[4][4] = {};
    for (int kc = 0; kc < DS; kc += 32) {
        __syncthreads();
#pragma unroll
        for (int pass = 0; pass < 2; ++pass) {
            int r = r8 + pass * 32;
            float4 sv = *(const float4*)(og + (by * 64 + r) * DS + kc + c4 * 4);
            float4 wvv = *(const float4*)(o_w + (bx * 64 + r) * DS + kc + c4 * 4);
            As[c4 * 4 + 0][r] = sv.x; As[c4 * 4 + 1][r] = sv.y;
            As[c4 * 4 + 2][r] = sv.z; As[c4 * 4 + 3][r] = sv.w;
            Ws[c4 * 4 + 0][r] = wvv.x; Ws[c4 * 4 + 1][r] = wvv.y;
            Ws[c4 * 4 + 2][r] = wvv.z; Ws[c4 * 4 + 3][r] = wvv.w;
        }
        __syncthreads();
#pragma unroll
        for (int k = 0; k < 32; ++k) {
            float4 a4 = *(const float4*)&As[k][ty * 4];
            float4 b4 = *(const float4*)&Ws[k][tx * 4];
            acc[0][0] += a4.x * b4.x; acc[0][1] += a4.x * b4.y; acc[0][2] += a4.x * b4.z; acc[0][3] += a4.x * b4.w;
            acc[1][0] += a4.y * b4.x; acc[1][1] += a4.y * b4.y; acc[1][2] += a4.y * b4.z; acc[1][3] += a4.y * b4.w;
            acc[2][0] += a4.z * b4.x; acc[2][1] += a4.z * b4.y; acc[2][2] += a4.z * b4.z; acc[2][3] += a4.z * b4.w;
            acc[3][0] += a4.w * b4.x; acc[3][1] += a4.w * b4.y; acc[3][2] += a4.w * b4.z; acc[3][3] += a4.w * b4.w;
        }
    }

    const int r0 = by * 64 + ty * 4;
    const int c0 = bx * 64 + tx * 4;
#pragma unroll
    for (int ii = 0; ii < 4; ++ii) {
        float4 v;
        v.x = acc[ii][0]; v.y = acc[ii][1]; v.z = acc[ii][2]; v.w = acc[ii][3];
        *(float4*)(out + (r0 + ii) * DS + c0) = v;
    }
}

extern "C" void kernel_launch(void* const* d_in, const int* in_sizes, int n_in,
                              void* d_out, int out_size, void* d_ws, size_t ws_size,
                              hipStream_t stream)
{
    const float* s      = (const float*)d_in[0];
    const float* z      = (const float*)d_in[1];
    const float* mask   = (const float*)d_in[2];
    const float* q_w    = (const float*)d_in[3];
    const float* q_b    = (const float*)d_in[4];
    const float* k_w    = (const float*)d_in[5];
    const float* v_w    = (const float*)d_in[6];
    const float* g_w    = (const float*)d_in[7];
    const float* o_w    = (const float*)d_in[8];
    const float* z_ln_w = (const float*)d_in[9];
    const float* z_ln_b = (const float*)d_in[10];
    const float* z_w    = (const float*)d_in[11];

    float* Q  = (float*)d_ws;
    float* K  = Q + S * DS;
    float* VT = K + S * DS;
    float* G  = VT + S * DS;
    float* og = G + S * DS;
    float* scores = og + S * DS;            // H*S*S floats = 16.8 MB

    hipLaunchKernelGGL(proj_kernel, dim3(192), dim3(256), 0, stream,
                       s, q_w, q_b, k_w, v_w, g_w, Q, K, VT, G);
    hipLaunchKernelGGL(score_kernel, dim3(S * 4), dim3(256), 0, stream,
                       z, mask, z_ln_w, z_ln_b, z_w, Q, K, scores);
    hipLaunchKernelGGL(spv_kernel, dim3(S), dim3(256), 0, stream,
                       scores, VT, G, og);
    hipLaunchKernelGGL(out_kernel, dim3(48), dim3(256), 0, stream,
                       og, o_w, (float*)d_out);
}

// Round 7
// 338.879 us; speedup vs baseline: 1.2410x; 1.2410x over previous
//
#include <hip/hip_runtime.h>

#define H 16
#define D 24
#define DS 384
#define CZ 128
#define S 512
#define EPSV 1e-5f

// ================= Kernel 1: tiled Q/K/V/G projections =================
// V now stored in NATURAL [S][H*D] layout (same as K) -> all stores coalesced float4.
__global__ __launch_bounds__(256) void proj_kernel(
    const float* __restrict__ s, const float* __restrict__ q_w, const float* __restrict__ q_b,
    const float* __restrict__ k_w, const float* __restrict__ v_w, const float* __restrict__ g_w,
    float* __restrict__ Q, float* __restrict__ K, float* __restrict__ V, float* __restrict__ G)
{
    const int b = blockIdx.x;
    const int mat = b / 48;          // 0:Q 1:K 2:V 3:G
    const int t = b % 48;
    const int by = t / 6, bx = t % 6;
    const float* w = (mat == 0) ? q_w : (mat == 1) ? k_w : (mat == 2) ? v_w : g_w;

    __shared__ float As[32][68];
    __shared__ float Ws[32][68];

    const int tid = threadIdx.x;
    const int tx = tid & 15, ty = tid >> 4;
    const int r8 = tid >> 3;
    const int c4 = tid & 7;

    float acc[4][4] = {};
    for (int kc = 0; kc < DS; kc += 32) {
        __syncthreads();
#pragma unroll
        for (int pass = 0; pass < 2; ++pass) {
            int r = r8 + pass * 32;
            float4 sv = *(const float4*)(s + (by * 64 + r) * DS + kc + c4 * 4);
            float4 wv = *(const float4*)(w + (bx * 64 + r) * DS + kc + c4 * 4);
            As[c4 * 4 + 0][r] = sv.x; As[c4 * 4 + 1][r] = sv.y;
            As[c4 * 4 + 2][r] = sv.z; As[c4 * 4 + 3][r] = sv.w;
            Ws[c4 * 4 + 0][r] = wv.x; Ws[c4 * 4 + 1][r] = wv.y;
            Ws[c4 * 4 + 2][r] = wv.z; Ws[c4 * 4 + 3][r] = wv.w;
        }
        __syncthreads();
#pragma unroll
        for (int k = 0; k < 32; ++k) {
            float4 a4 = *(const float4*)&As[k][ty * 4];
            float4 b4 = *(const float4*)&Ws[k][tx * 4];
            acc[0][0] += a4.x * b4.x; acc[0][1] += a4.x * b4.y; acc[0][2] += a4.x * b4.z; acc[0][3] += a4.x * b4.w;
            acc[1][0] += a4.y * b4.x; acc[1][1] += a4.y * b4.y; acc[1][2] += a4.y * b4.z; acc[1][3] += a4.y * b4.w;
            acc[2][0] += a4.z * b4.x; acc[2][1] += a4.z * b4.y; acc[2][2] += a4.z * b4.z; acc[2][3] += a4.z * b4.w;
            acc[3][0] += a4.w * b4.x; acc[3][1] += a4.w * b4.y; acc[3][2] += a4.w * b4.z; acc[3][3] += a4.w * b4.w;
        }
    }

    const int r0 = by * 64 + ty * 4;
    const int c0 = bx * 64 + tx * 4;
    float* dst = (mat == 0) ? Q : (mat == 1) ? K : (mat == 2) ? V : G;
#pragma unroll
    for (int ii = 0; ii < 4; ++ii) {
        float4 v;
        v.x = acc[ii][0]; v.y = acc[ii][1]; v.z = acc[ii][2]; v.w = acc[ii][3];
        if (mat == 0) {
            v.x += q_b[c0 + 0]; v.y += q_b[c0 + 1]; v.z += q_b[c0 + 2]; v.w += q_b[c0 + 3];
        } else if (mat == 3) {
            v.x = 1.f / (1.f + __expf(-v.x)); v.y = 1.f / (1.f + __expf(-v.y));
            v.z = 1.f / (1.f + __expf(-v.z)); v.w = 1.f / (1.f + __expf(-v.w));
        }
        *(float4*)(dst + (r0 + ii) * DS + c0) = v;
    }
}

// ================= Kernel 2a: register-z + broadcast-a LN/bias/QK scores (r3, 98us) =================
__global__ __launch_bounds__(256) void score_kernel(
    const float* __restrict__ z, const float* __restrict__ seq_mask,
    const float* __restrict__ z_ln_w, const float* __restrict__ z_ln_b,
    const float* __restrict__ z_w,
    const float* __restrict__ Q, const float* __restrict__ K,
    float* __restrict__ scores)
{
    const int b = blockIdx.x;
    const int q = b >> 3;
    const int j0 = (b & 7) * 64;
    const int tid = threadIdx.x;
    const int w = tid >> 6;        // wave id -> channel slice
    const int lane = tid & 63;     // key row within tile

    __shared__ float a_s[H][CZ + 4];      // folded lnw*zw        8.4 KB
    __shared__ float AhBh[2][H];          //                      128 B
    __shared__ float qrow[DS];            //                      1.5 KB
    __shared__ float stats[4][2][68];     // [wave][sum/sq][row]  2.2 KB
    __shared__ float opart[4][H][68];     // [wave][head][row]    17.4 KB
    __shared__ float buf[H][68];          // output transpose     4.3 KB

    // ---- Phase 0: stage a_s (+Ah/Bh) and qrow ----
    {
        const int h = tid >> 4;           // 0..15
        const int c8 = (tid & 15) * 8;    // 8 channels each
        float A = 0.f, Bv = 0.f;
#pragma unroll
        for (int p = 0; p < 2; ++p) {
            float4 wz = *(const float4*)(z_w + h * CZ + c8 + p * 4);
            float4 lw = *(const float4*)(z_ln_w + c8 + p * 4);
            float4 lb = *(const float4*)(z_ln_b + c8 + p * 4);
            float4 a;
            a.x = lw.x * wz.x; a.y = lw.y * wz.y; a.z = lw.z * wz.z; a.w = lw.w * wz.w;
            *(float4*)&a_s[h][c8 + p * 4] = a;
            A += a.x + a.y + a.z + a.w;
            Bv += lb.x * wz.x + lb.y * wz.y + lb.z * wz.z + lb.w * wz.w;
        }
#pragma unroll
        for (int m = 1; m < 16; m <<= 1) {
            A += __shfl_xor(A, m);
            Bv += __shfl_xor(Bv, m);
        }
        if ((tid & 15) == 0) { AhBh[0][h] = A; AhBh[1][h] = Bv; }
    }
    for (int i = tid; i < DS; i += 256) qrow[i] = Q[q * DS + i];
    __syncthreads();

    // ---- Phase 1: per-wave partial GEMM over its 32-channel slice ----
    {
        const int c0 = w * 32;
        const float* zr = z + ((long)q * S + j0 + lane) * CZ + c0;
        float4 zf[8];
#pragma unroll
        for (int t = 0; t < 8; ++t) zf[t] = *(const float4*)(zr + t * 4);

        float s1 = 0.f, s2 = 0.f;
#pragma unroll
        for (int t = 0; t < 8; ++t) {
            s1 += zf[t].x + zf[t].y + zf[t].z + zf[t].w;
            s2 += zf[t].x * zf[t].x + zf[t].y * zf[t].y + zf[t].z * zf[t].z + zf[t].w * zf[t].w;
        }
        stats[w][0][lane] = s1;
        stats[w][1][lane] = s2;

#pragma unroll
        for (int h = 0; h < H; ++h) {
            float acc = 0.f;
#pragma unroll
            for (int t = 0; t < 8; ++t) {
                float4 a4 = *(const float4*)&a_s[h][c0 + t * 4];   // wave-uniform: broadcast
                acc += zf[t].x * a4.x + zf[t].y * a4.y + zf[t].z * a4.z + zf[t].w * a4.w;
            }
            opart[w][h][lane] = acc;
        }
    }
    __syncthreads();

    // ---- Phase 2: combine partials, LN affine + QK, write via transpose buffer ----
    {
        const int r = tid >> 2;           // key row 0..63
        const int hq = tid & 3;           // head quad
        float s1 = stats[0][0][r] + stats[1][0][r] + stats[2][0][r] + stats[3][0][r];
        float s2 = stats[0][1][r] + stats[1][1][r] + stats[2][1][r] + stats[3][1][r];
        const float mu = s1 * (1.f / 128.f);
        const float rs = rsqrtf(s2 * (1.f / 128.f) - mu * mu + EPSV);
        const float mk = seq_mask[j0 + r];
        const float scale = 0.2041241452319315f;  // 1/sqrt(24)
        const float* krow = K + (long)(j0 + r) * DS;

#pragma unroll
        for (int i = 0; i < 4; ++i) {
            const int h = hq * 4 + i;
            float dza = opart[0][h][r] + opart[1][h][r] + opart[2][h][r] + opart[3][h][r];
            const float4* k4 = (const float4*)(krow + h * D);
            const float4* q4 = (const float4*)(qrow + h * D);
            float qk = 0.f;
#pragma unroll
            for (int t = 0; t < 6; ++t) {
                float4 kv = k4[t];
                float4 qv = q4[t];
                qk += kv.x * qv.x + kv.y * qv.y + kv.z * qv.z + kv.w * qv.w;
            }
            const float bias = rs * dza - mu * rs * AhBh[0][h] + AhBh[1][h];
            buf[h][r] = qk * scale + bias + mk;
        }
    }
    __syncthreads();

    // coalesced store: 16 threads per head, float4 along j
    {
        const int h = tid >> 4, j4 = tid & 15;
        float4 v = *(const float4*)&buf[h][j4 * 4];
        *(float4*)(scores + ((q << 4) + h) * S + j0 + j4 * 4) = v;
    }
}

// ================= Kernel 2b: softmax + PV + gate, COALESCED V =================
// PV reordered: o[c] = sum_j p[h(c)][j] * V[j][c] with V natural [S][H*D].
// Wave wv owns j-quarter; lane owns 4 consecutive c. Every V load is a contiguous
// 1-KB wave instruction (8 lines) vs the old per-lane 2KB-stride gather (64 lines).
// sc[h][j] LDS reads: <=16 distinct addrs, h/h+8 2-way bank alias = free.
__global__ __launch_bounds__(256) void spv_kernel(
    const float* __restrict__ scores, const float* __restrict__ V,
    const float* __restrict__ G, float* __restrict__ og)
{
    const int q = blockIdx.x;
    const int tid = threadIdx.x;
    const int wv = tid >> 6;
    const int lane = tid & 63;

    __shared__ float sc[H][S + 4];
    __shared__ float opart[4][DS];
    __shared__ float inv_l[H];

    for (int i = tid; i < H * (S / 4); i += 256) {
        int row = i >> 7, f4 = i & 127;
        float4 v = ((const float4*)(scores + ((q << 4) + row) * S))[f4];
        *(float4*)&sc[row][f4 * 4] = v;
    }
    __syncthreads();

#pragma unroll
    for (int i = 0; i < 4; ++i) {
        int h = wv * 4 + i;
        float m = -1e30f;
        for (int j = lane; j < S; j += 64) m = fmaxf(m, sc[h][j]);
#pragma unroll
        for (int mk = 1; mk < 64; mk <<= 1) m = fmaxf(m, __shfl_xor(m, mk));
        float sum = 0.f;
        for (int j = lane; j < S; j += 64) {
            float p = __expf(sc[h][j] - m);
            sc[h][j] = p;
            sum += p;
        }
#pragma unroll
        for (int mk = 1; mk < 64; mk <<= 1) sum += __shfl_xor(sum, mk);
        if (lane == 0) inv_l[h] = 1.f / sum;
    }
    __syncthreads();

    // ---- PV: wave wv -> j in [wv*128, wv*128+128); lane -> c0 = lane*4 (+ c1 for lane<32)
    {
        const int jb = wv * 128;
        const int c0 = lane * 4;
        const int h0 = c0 / 24;
        const int c1 = 256 + lane * 4;            // only lanes 0..31
        const int h1 = c1 / 24;                   // <=15 for lane<32
        float4 a0 = {0.f, 0.f, 0.f, 0.f};
        float4 a1 = {0.f, 0.f, 0.f, 0.f};
#pragma unroll 4
        for (int jj = 0; jj < 128; ++jj) {
            const int j = jb + jj;
            const float4* vr = (const float4*)(V + (long)j * DS);
            const float p0 = sc[h0][j];
            float4 v0 = vr[lane];
            a0.x += p0 * v0.x; a0.y += p0 * v0.y; a0.z += p0 * v0.z; a0.w += p0 * v0.w;
            if (lane < 32) {
                const float p1 = sc[h1][j];
                float4 v1 = vr[64 + lane];
                a1.x += p1 * v1.x; a1.y += p1 * v1.y; a1.z += p1 * v1.z; a1.w += p1 * v1.w;
            }
        }
        *(float4*)&opart[wv][c0] = a0;
        if (lane < 32) *(float4*)&opart[wv][c1] = a1;
    }
    __syncthreads();
    for (int i = tid; i < DS; i += 256) {
        float o = opart[0][i] + opart[1][i] + opart[2][i] + opart[3][i];
        int h = i / 24;
        og[q * DS + i] = o * inv_l[h] * G[q * DS + i];
    }
}

// ================= Kernel 3: tiled output projection (baseline, passing) =================
__global__ __launch_bounds__(256) void out_kernel(
    const float* __restrict__ og, const float* __restrict__ o_w, float* __restrict__ out)
{
    const int b = blockIdx.x;
    const int by = b / 6, bx = b % 6;

    __shared__ float As[32][68];
    __shared__ float Ws[32][68];

    const int tid = threadIdx.x;
    const int tx = tid & 15, ty = tid >> 4;
    const int r8 = tid >> 3;
    const int c4 = tid & 7;

    float acc[4][4] = {};
    for (int kc = 0; kc < DS; kc += 32) {
        __syncthreads();
#pragma unroll
        for (int pass = 0; pass < 2; ++pass) {
            int r = r8 + pass * 32;
            float4 sv = *(const float4*)(og + (by * 64 + r) * DS + kc + c4 * 4);
            float4 wvv = *(const float4*)(o_w + (bx * 64 + r) * DS + kc + c4 * 4);
            As[c4 * 4 + 0][r] = sv.x; As[c4 * 4 + 1][r] = sv.y;
            As[c4 * 4 + 2][r] = sv.z; As[c4 * 4 + 3][r] = sv.w;
            Ws[c4 * 4 + 0][r] = wvv.x; Ws[c4 * 4 + 1][r] = wvv.y;
            Ws[c4 * 4 + 2][r] = wvv.z; Ws[c4 * 4 + 3][r] = wvv.w;
        }
        __syncthreads();
#pragma unroll
        for (int k = 0; k < 32; ++k) {
            float4 a4 = *(const float4*)&As[k][ty * 4];
            float4 b4 = *(const float4*)&Ws[k][tx * 4];
            acc[0][0] += a4.x * b4.x; acc[0][1] += a4.x * b4.y; acc[0][2] += a4.x * b4.z; acc[0][3] += a4.x * b4.w;
            acc[1][0] += a4.y * b4.x; acc[1][1] += a4.y * b4.y; acc[1][2] += a4.y * b4.z; acc[1][3] += a4.y * b4.w;
            acc[2][0] += a4.z * b4.x; acc[2][1] += a4.z * b4.y; acc[2][2] += a4.z * b4.z; acc[2][3] += a4.z * b4.w;
            acc[3][0] += a4.w * b4.x; acc[3][1] += a4.w * b4.y; acc[3][2] += a4.w * b4.z; acc[3][3] += a4.w * b4.w;
        }
    }

    const int r0 = by * 64 + ty * 4;
    const int c0 = bx * 64 + tx * 4;
#pragma unroll
    for (int ii = 0; ii < 4; ++ii) {
        float4 v;
        v.x = acc[ii][0]; v.y = acc[ii][1]; v.z = acc[ii][2]; v.w = acc[ii][3];
        *(float4*)(out + (r0 + ii) * DS + c0) = v;
    }
}

extern "C" void kernel_launch(void* const* d_in, const int* in_sizes, int n_in,
                              void* d_out, int out_size, void* d_ws, size_t ws_size,
                              hipStream_t stream)
{
    const float* s      = (const float*)d_in[0];
    const float* z      = (const float*)d_in[1];
    const float* mask   = (const float*)d_in[2];
    const float* q_w    = (const float*)d_in[3];
    const float* q_b    = (const float*)d_in[4];
    const float* k_w    = (const float*)d_in[5];
    const float* v_w    = (const float*)d_in[6];
    const float* g_w    = (const float*)d_in[7];
    const float* o_w    = (const float*)d_in[8];
    const float* z_ln_w = (const float*)d_in[9];
    const float* z_ln_b = (const float*)d_in[10];
    const float* z_w    = (const float*)d_in[11];

    float* Q  = (float*)d_ws;
    float* K  = Q + S * DS;
    float* V  = K + S * DS;                 // natural [S][H*D] layout now
    float* G  = V + S * DS;
    float* og = G + S * DS;
    float* scores = og + S * DS;            // H*S*S floats = 16.8 MB

    hipLaunchKernelGGL(proj_kernel, dim3(192), dim3(256), 0, stream,
                       s, q_w, q_b, k_w, v_w, g_w, Q, K, V, G);
    hipLaunchKernelGGL(score_kernel, dim3(4096), dim3(256), 0, stream,
                       z, mask, z_ln_w, z_ln_b, z_w, Q, K, scores);
    hipLaunchKernelGGL(spv_kernel, dim3(S), dim3(256), 0, stream,
                       scores, V, G, og);
    hipLaunchKernelGGL(out_kernel, dim3(48), dim3(256), 0, stream,
                       og, o_w, (float*)d_out);
}